// Round 5
// baseline (306.707 us; speedup 1.0000x reference)
//
#include <hip/hip_runtime.h>

#define D_MODEL 1024
#define N_HEADS 16
#define D_KH    64
#define BATCH   4
#define SEQ     2048
#define M_TOTAL (BATCH*SEQ)   // 8192

typedef __attribute__((ext_vector_type(8))) short short8;
typedef __attribute__((ext_vector_type(4))) float f32x4;
typedef __attribute__((ext_vector_type(4))) unsigned short u16x4;
typedef __attribute__((ext_vector_type(2))) unsigned int u32x2;

__device__ __forceinline__ unsigned short f2bf(float f) {
  union { float f; unsigned u; } v; v.f = f;
  unsigned r = v.u + 0x7FFFu + ((v.u >> 16) & 1u);
  return (unsigned short)(r >> 16);
}
__device__ __forceinline__ unsigned fbits(float f) {
  union { float f; unsigned u; } v; v.f = f; return v.u;
}
// LDS swizzle for bf16 [R][64] tiles: XOR row bits into the 16B-granule
// index (elem bits 3..5). Bijective per row; writes and reads use the same
// involution. 8B accesses at 4-aligned col stay within one granule.
// Verified r4: conflicts 8.3M -> 2.5M with this scheme.
__device__ __forceinline__ int sw(int row, int col) {
  return row * 64 + (col ^ ((row & 7) << 3));
}

// ---------------------------------------------------------------- cvt_q
__global__ __launch_bounds__(256) void cvt_q(const float* __restrict__ Q,
                                             unsigned short* __restrict__ Qbf) {
  size_t i = (size_t)blockIdx.x * 256 + threadIdx.x;
  float4 v = ((const float4*)Q)[i];
  u16x4 o;
  o[0] = f2bf(v.x); o[1] = f2bf(v.y); o[2] = f2bf(v.z); o[3] = f2bf(v.w);
  ((u16x4*)Qbf)[i] = o;
}

// ---------------------------------------------------------------- cvt_wt
__global__ __launch_bounds__(256) void cvt_wt(const float* __restrict__ Wq,
                                              const float* __restrict__ Wk,
                                              const float* __restrict__ Wv,
                                              unsigned short* __restrict__ WT) {
  const int z = blockIdx.z;
  const float* W = (z == 0) ? Wq : (z == 1) ? Wk : Wv;
  __shared__ float tile[32][33];
  const int k0 = blockIdx.y * 32, n0 = blockIdx.x * 32;
  const int tx = threadIdx.x & 31, ty = threadIdx.x >> 5;
  for (int i = 0; i < 4; ++i)
    tile[ty + i * 8][tx] = W[(size_t)(k0 + ty + i * 8) * D_MODEL + n0 + tx];
  __syncthreads();
  unsigned short* out = WT + (size_t)z * D_MODEL * D_MODEL;
  for (int i = 0; i < 4; ++i)
    out[(size_t)(n0 + ty + i * 8) * D_MODEL + k0 + tx] = f2bf(tile[tx][ty + i * 8]);
}

// ---------------------------------------------------------------- gemm_qkv
// (unchanged from round 3 -- verified: fused M=8192 x N=3072, BK=64 dbuf,
//  counted vmcnt(8), T2 swizzle, XCD-bijective m-outer block swizzle)
#define GQ_BM 128
#define GQ_BN 128
#define GQ_BK 64
#define GQ_NT (D_MODEL / GQ_BK)   // 16

__global__ __launch_bounds__(256, 2) void gemm_qkv(
    const unsigned short* __restrict__ Qbf,
    const unsigned short* __restrict__ WT,
    const float* __restrict__ bq_p, const float* __restrict__ bk_p,
    const float* __restrict__ bv_p,
    float* __restrict__ out_qa,
    unsigned short* __restrict__ kbf,
    unsigned short* __restrict__ vt) {
  const int f   = blockIdx.x;                 // 0..1535
  const int swz = (f & 7) * 192 + (f >> 3);   // XCD-bijective (1536%8==0)
  const int mm  = swz / 24;                   // 0..63  (m-outer)
  const int nn  = swz % 24;                   // 0..23
  const int m0  = mm * GQ_BM;
  const int n0g = nn * GQ_BN;                 // global col in [0,3072)
  const int z   = n0g >> 10;                  // block-uniform (1024%128==0)
  const int n0  = n0g & 1023;

  __shared__ unsigned short smA[2][GQ_BM * GQ_BK];  // 16 KB each
  __shared__ unsigned short smB[2][GQ_BN * GQ_BK];  // total 64 KB

  const int t    = threadIdx.x;
  const int lane = t & 63;
  const int w    = t >> 6;
  const int quad = lane >> 4;
  const int l16  = lane & 15;
  const int wr   = w >> 1, wc = w & 1;

  f32x4 acc[4][4];
  for (int i = 0; i < 4; ++i)
    for (int j = 0; j < 4; ++j) acc[i][j] = (f32x4){0.f, 0.f, 0.f, 0.f};

  auto stage = [&](int p, int kt) {
    #pragma unroll
    for (int r = 0; r < 4; ++r) {
      int o   = (r * 256 + t) * 8;                 // elem offset in [0,8192)
      int row = o >> 6;                            // tile row 0..127
      int col = (o & 63) ^ ((row & 7) << 3);       // pre-swizzled k-col
      const unsigned short* ga = Qbf + (size_t)(m0 + row)  * D_MODEL + kt * 64 + col;
      const unsigned short* gb = WT  + (size_t)(n0g + row) * D_MODEL + kt * 64 + col;
      __builtin_amdgcn_global_load_lds(
          (const __attribute__((address_space(1))) void*)ga,
          (__attribute__((address_space(3))) void*)&smA[p][o], 16, 0, 0);
      __builtin_amdgcn_global_load_lds(
          (const __attribute__((address_space(1))) void*)gb,
          (__attribute__((address_space(3))) void*)&smB[p][o], 16, 0, 0);
    }
  };

  stage(0, 0);
  stage(1, 1);
  asm volatile("s_waitcnt vmcnt(8)" ::: "memory");
  __builtin_amdgcn_s_barrier();
  asm volatile("" ::: "memory");

  for (int kt = 0; kt < GQ_NT; ++kt) {
    const int p = kt & 1;

    short8 af[4][2], bf[4][2];
    #pragma unroll
    for (int mi = 0; mi < 4; ++mi) {
      int row = wr * 64 + mi * 16 + l16;
      #pragma unroll
      for (int kk = 0; kk < 2; ++kk)
        af[mi][kk] = *(const short8*)
            &smA[p][(row * 64 + kk * 32 + quad * 8) ^ ((row & 7) << 3)];
    }
    #pragma unroll
    for (int ni = 0; ni < 4; ++ni) {
      int row = wc * 64 + ni * 16 + l16;
      #pragma unroll
      for (int kk = 0; kk < 2; ++kk)
        bf[ni][kk] = *(const short8*)
            &smB[p][(row * 64 + kk * 32 + quad * 8) ^ ((row & 7) << 3)];
    }

    __builtin_amdgcn_s_setprio(1);
    #pragma unroll
    for (int mi = 0; mi < 4; ++mi)
      #pragma unroll
      for (int ni = 0; ni < 4; ++ni) {
        acc[mi][ni] = __builtin_amdgcn_mfma_f32_16x16x32_bf16(
            af[mi][0], bf[ni][0], acc[mi][ni], 0, 0, 0);
        acc[mi][ni] = __builtin_amdgcn_mfma_f32_16x16x32_bf16(
            af[mi][1], bf[ni][1], acc[mi][ni], 0, 0, 0);
      }
    __builtin_amdgcn_s_setprio(0);

    __builtin_amdgcn_s_barrier();            // everyone done reading buf p
    asm volatile("" ::: "memory");
    if (kt + 2 < GQ_NT) {
      stage(p, kt + 2);                      // refill vacated buffer
      asm volatile("s_waitcnt vmcnt(8)" ::: "memory");   // tile kt+1 landed
    } else {
      asm volatile("s_waitcnt vmcnt(0)" ::: "memory");   // drain at the end
    }
    __builtin_amdgcn_s_barrier();            // tile kt+1 visible to all
    asm volatile("" ::: "memory");
  }

  const float* bias = (z == 0) ? bq_p : (z == 1) ? bk_p : bv_p;
  if (z == 2) {
    for (int ni = 0; ni < 4; ++ni) {
      int n = n0 + wc * 64 + ni * 16 + l16;
      float bval = bias[n];
      int h = n >> 6, d = n & 63;
      for (int mi = 0; mi < 4; ++mi) {
        int m = m0 + wr * 64 + mi * 16 + quad * 4;
        int b = m >> 11, s = m & 2047;
        u16x4 o;
        for (int j = 0; j < 4; ++j) o[j] = f2bf(acc[mi][ni][j] + bval);
        *(u16x4*)&vt[(size_t)((b * 16 + h) * 64 + d) * SEQ + s] = o;
      }
    }
  } else {
    for (int ni = 0; ni < 4; ++ni) {
      int n = n0 + wc * 64 + ni * 16 + l16;
      float bval = bias[n];
      for (int mi = 0; mi < 4; ++mi) {
        int mbase = m0 + wr * 64 + mi * 16 + quad * 4;
        for (int j = 0; j < 4; ++j) {
          float v = acc[mi][ni][j] + bval;
          size_t idx = (size_t)(mbase + j) * D_MODEL + n;
          if (z == 0) out_qa[idx] = v;
          else        kbf[idx] = f2bf(v);
        }
      }
    }
  }
}

// ---------------------------------------------------------------- attn
// r2 structure (256 thr = 4 waves, wave owns TWO 16-q groups of the
// 128-q tile) with K/V LDS staging REMOVED: kf/vf fragments load
// directly from global (K/V tiles are 8 KB each -- L1/L2-resident; each
// fragment load covers 16 full 64B lines, same coalescing as the LDS
// path). This deletes the staging writes, the register-prefetch
// machinery, and ALL in-loop barriers -- waves run fully independent,
// so 16 waves/CU of TLP hide the L1/L2 latency the barrier-lockstep
// used to expose. LDS holds only the swizzled sQ/sP alias (16 KB).
#define QBLK 128

__global__ __launch_bounds__(256, 4) void attn(
    const float* __restrict__ qa,            // [8192,1024] fp32
    const unsigned short* __restrict__ kbf,  // [8192,1024] bf16
    const unsigned short* __restrict__ vt,   // [(bh)*64+d][2048] bf16 (V^T)
    const int* __restrict__ length,
    float* __restrict__ ctx) {               // [8192,1024] fp32
  const int flat = blockIdx.y * 16 + blockIdx.x;          // 0..1023
  const int low = flat & 3;
  const int mid = (flat >> 2) & 15;
  const int hi  = flat >> 6;                              // 0..15
  const int b  = (low + mid + (mid >> 2) + hi + (hi >> 2)) & 3;
  const int h  = mid;
  const int qt = hi;                                      // 128-q tile index
  const int bh = b * 16 + h;
  const int len = length[b];

  const int t    = threadIdx.x;
  const int lane = t & 63;
  const int w    = t >> 6;              // 0..3
  const int quad = lane >> 4;
  const int l16  = lane & 15;
  const int r8   = t >> 3;              // 0..31
  const int c8   = (t & 7) * 8;         // 0,8,..,56

  __shared__ unsigned short sQP[QBLK * 64];  // [q][64] swizzled; Q then P
  unsigned short* const sP = sQP;            // alias (Q consumed first)

  const float SCL = 0.125f * 1.44269504f;   // 1/sqrt(64) * log2(e)

  // stage Q tile (fp32 -> bf16, pre-scaled): 128 rows x 64 d
  for (int half = 0; half < 4; ++half) {
    int r = r8 + half * 32;
    const float* src = qa + (size_t)(b * SEQ + qt * QBLK + r) * D_MODEL + h * D_KH + c8;
    float4 v0 = *(const float4*)src;
    float4 v1 = *(const float4*)(src + 4);
    short8 o;
    o[0] = (short)f2bf(v0.x * SCL); o[1] = (short)f2bf(v0.y * SCL);
    o[2] = (short)f2bf(v0.z * SCL); o[3] = (short)f2bf(v0.w * SCL);
    o[4] = (short)f2bf(v1.x * SCL); o[5] = (short)f2bf(v1.y * SCL);
    o[6] = (short)f2bf(v1.z * SCL); o[7] = (short)f2bf(v1.w * SCL);
    *(short8*)&sQP[sw(r, c8)] = o;
  }
  __syncthreads();   // the ONLY barrier

  const int qr0 = w * 16 + l16;
  const int qr1 = 64 + qr0;
  short8 qf00 = *(const short8*)&sQP[sw(qr0, quad * 8)];
  short8 qf01 = *(const short8*)&sQP[sw(qr0, 32 + quad * 8)];
  short8 qf10 = *(const short8*)&sQP[sw(qr1, quad * 8)];
  short8 qf11 = *(const short8*)&sQP[sw(qr1, 32 + quad * 8)];

  f32x4 acc0[4], acc1[4];
  for (int i = 0; i < 4; ++i) {
    acc0[i] = (f32x4){0.f, 0.f, 0.f, 0.f};
    acc1[i] = (f32x4){0.f, 0.f, 0.f, 0.f};
  }
  float den0 = 0.f, den1 = 0.f;

  // per-lane fragment base pointers (advance by one key-tile per iter)
  const unsigned short* kfp = kbf + (size_t)b * SEQ * D_MODEL + h * D_KH
                              + (size_t)l16 * D_MODEL + quad * 8;   // row l16
  const unsigned short* vfp = vt + (size_t)bh * 64 * SEQ
                              + (size_t)l16 * SEQ + quad * 8;       // d-row l16

  const int nkt = (len + 63) >> 6;

  for (int kt = 0; kt < nkt; ++kt) {
    const bool full = ((kt + 1) << 6) <= len;   // block-uniform

    // K fragments for this tile: key rows kt*64 + n*16 + l16, d cols
    // quad*8(+32). 8 independent b128 loads, issued up front.
    short8 kf[4][2];
    #pragma unroll
    for (int n = 0; n < 4; ++n) {
      const unsigned short* kp = kfp + (size_t)(kt * 64 + n * 16) * D_MODEL;
      kf[n][0] = *(const short8*)kp;
      kf[n][1] = *(const short8*)(kp + 32);
    }

    // S^T = K.Q^T for both q-groups; kf shared across groups.
    #pragma unroll
    for (int n = 0; n < 4; ++n) {
      f32x4 s0 = (f32x4){0.f, 0.f, 0.f, 0.f};
      s0 = __builtin_amdgcn_mfma_f32_16x16x32_bf16(kf[n][0], qf00, s0, 0, 0, 0);
      s0 = __builtin_amdgcn_mfma_f32_16x16x32_bf16(kf[n][1], qf01, s0, 0, 0, 0);
      f32x4 s1 = (f32x4){0.f, 0.f, 0.f, 0.f};
      s1 = __builtin_amdgcn_mfma_f32_16x16x32_bf16(kf[n][0], qf10, s1, 0, 0, 0);
      s1 = __builtin_amdgcn_mfma_f32_16x16x32_bf16(kf[n][1], qf11, s1, 0, 0, 0);

      float e0, e1, e2, e3, f0, f1, f2, f3;
      if (full) {
        e0 = exp2f(s0[0]); e1 = exp2f(s0[1]); e2 = exp2f(s0[2]); e3 = exp2f(s0[3]);
        f0 = exp2f(s1[0]); f1 = exp2f(s1[1]); f2 = exp2f(s1[2]); f3 = exp2f(s1[3]);
      } else {
        int kb = kt * 64 + n * 16 + quad * 4;
        e0 = (kb + 0 < len) ? exp2f(s0[0]) : 0.f;
        e1 = (kb + 1 < len) ? exp2f(s0[1]) : 0.f;
        e2 = (kb + 2 < len) ? exp2f(s0[2]) : 0.f;
        e3 = (kb + 3 < len) ? exp2f(s0[3]) : 0.f;
        f0 = (kb + 0 < len) ? exp2f(s1[0]) : 0.f;
        f1 = (kb + 1 < len) ? exp2f(s1[1]) : 0.f;
        f2 = (kb + 2 < len) ? exp2f(s1[2]) : 0.f;
        f3 = (kb + 3 < len) ? exp2f(s1[3]) : 0.f;
      }
      den0 += (e0 + e1) + (e2 + e3);
      den1 += (f0 + f1) + (f2 + f3);
      u32x2 pk;
      pk[0] = __builtin_amdgcn_perm(fbits(e1), fbits(e0), 0x07060302);
      pk[1] = __builtin_amdgcn_perm(fbits(e3), fbits(e2), 0x07060302);
      *(u32x2*)&sP[sw(qr0, n * 16 + quad * 4)] = pk;
      u32x2 pk1;
      pk1[0] = __builtin_amdgcn_perm(fbits(f1), fbits(f0), 0x07060302);
      pk1[1] = __builtin_amdgcn_perm(fbits(f3), fbits(f2), 0x07060302);
      *(u32x2*)&sP[sw(qr1, n * 16 + quad * 4)] = pk1;
    }
    // sP rows are per-wave -> no barrier (same-wave RAW via lgkmcnt)

    // V fragments: d-rows n2*16 + l16, key cols kt*64 + quad*8(+32).
    short8 vf[4][2];
    #pragma unroll
    for (int n2 = 0; n2 < 4; ++n2) {
      const unsigned short* vp = vfp + (size_t)(n2 * 16) * SEQ + kt * 64;
      vf[n2][0] = *(const short8*)vp;
      vf[n2][1] = *(const short8*)(vp + 32);
    }

    short8 pf00 = *(const short8*)&sP[sw(qr0, quad * 8)];
    short8 pf01 = *(const short8*)&sP[sw(qr0, 32 + quad * 8)];
    short8 pf10 = *(const short8*)&sP[sw(qr1, quad * 8)];
    short8 pf11 = *(const short8*)&sP[sw(qr1, 32 + quad * 8)];
    #pragma unroll
    for (int n2 = 0; n2 < 4; ++n2) {
      acc0[n2] = __builtin_amdgcn_mfma_f32_16x16x32_bf16(vf[n2][0], pf00, acc0[n2], 0, 0, 0);
      acc0[n2] = __builtin_amdgcn_mfma_f32_16x16x32_bf16(vf[n2][1], pf01, acc0[n2], 0, 0, 0);
      acc1[n2] = __builtin_amdgcn_mfma_f32_16x16x32_bf16(vf[n2][0], pf10, acc1[n2], 0, 0, 0);
      acc1[n2] = __builtin_amdgcn_mfma_f32_16x16x32_bf16(vf[n2][1], pf11, acc1[n2], 0, 0, 0);
    }
  }

  den0 += __shfl_xor(den0, 16, 64);
  den0 += __shfl_xor(den0, 32, 64);
  den1 += __shfl_xor(den1, 16, 64);
  den1 += __shfl_xor(den1, 32, 64);
  float inv0 = 1.f / (den0 + 1e-8f);
  float inv1 = 1.f / (den1 + 1e-8f);

  {
    int q0 = qt * QBLK + w * 16 + l16;
    float* dst0 = ctx + (size_t)(b * SEQ + q0) * D_MODEL + h * D_KH;
    float* dst1 = dst0 + (size_t)64 * D_MODEL;   // q0 + 64
    for (int n2 = 0; n2 < 4; ++n2) {
      f32x4 o0 = acc0[n2];
      f32x4 o1 = acc1[n2];
      *(float4*)(dst0 + n2 * 16 + quad * 4) =
          make_float4(o0[0] * inv0, o0[1] * inv0, o0[2] * inv0, o0[3] * inv0);
      *(float4*)(dst1 + n2 * 16 + quad * 4) =
          make_float4(o1[0] * inv1, o1[1] * inv1, o1[2] * inv1, o1[3] * inv1);
    }
  }
}

// ---------------------------------------------------------------- launch
extern "C" void kernel_launch(void* const* d_in, const int* in_sizes, int n_in,
                              void* d_out, int out_size, void* d_ws, size_t ws_size,
                              hipStream_t stream) {
  const float* Q      = (const float*)d_in[0];
  const int*   length = (const int*)d_in[1];
  const float* Wq     = (const float*)d_in[2];
  const float* bq     = (const float*)d_in[3];
  const float* Wk     = (const float*)d_in[4];
  const float* bk     = (const float*)d_in[5];
  const float* Wv     = (const float*)d_in[6];
  const float* bv     = (const float*)d_in[7];

  float* out_ctx = (float*)d_out;                         // [8192,1024]
  float* out_qa  = out_ctx + (size_t)M_TOTAL * D_MODEL;   // [8192,1024]

  char* ws = (char*)d_ws;
  unsigned short* Qbf = (unsigned short*)ws;                              // 16 MB
  unsigned short* WT  = (unsigned short*)(ws + (size_t)16 * 1024 * 1024); //  6 MB
  unsigned short* Kbf = (unsigned short*)(ws + (size_t)22 * 1024 * 1024); // 16 MB
  unsigned short* Vt  = (unsigned short*)(ws + (size_t)38 * 1024 * 1024); // 16 MB

  hipLaunchKernelGGL(cvt_q, dim3((M_TOTAL * D_MODEL) / (256 * 4)), dim3(256), 0, stream,
                     Q, Qbf);
  hipLaunchKernelGGL(cvt_wt, dim3(32, 32, 3), dim3(256), 0, stream, Wq, Wk, Wv, WT);
  hipLaunchKernelGGL(gemm_qkv, dim3(64 * 24), dim3(256), 0, stream,
                     Qbf, WT, bq, bk, bv, out_qa, Kbf, Vt);
  hipLaunchKernelGGL(attn, dim3(SEQ / QBLK, BATCH * N_HEADS), dim3(256), 0, stream,
                     out_qa, Kbf, Vt, length, out_ctx);
}

// Round 6
// 285.062 us; speedup vs baseline: 1.0759x; 1.0759x over previous
//
#include <hip/hip_runtime.h>

#define D_MODEL 1024
#define N_HEADS 16
#define D_KH    64
#define BATCH   4
#define SEQ     2048
#define M_TOTAL (BATCH*SEQ)   // 8192

typedef __attribute__((ext_vector_type(8))) short short8;
typedef __attribute__((ext_vector_type(4))) float f32x4;
typedef __attribute__((ext_vector_type(4))) unsigned short u16x4;
typedef __attribute__((ext_vector_type(2))) unsigned int u32x2;

__device__ __forceinline__ unsigned short f2bf(float f) {
  union { float f; unsigned u; } v; v.f = f;
  unsigned r = v.u + 0x7FFFu + ((v.u >> 16) & 1u);
  return (unsigned short)(r >> 16);
}
__device__ __forceinline__ unsigned fbits(float f) {
  union { float f; unsigned u; } v; v.f = f; return v.u;
}
// LDS swizzle for bf16 [R][64] tiles: XOR row bits into the 16B-granule
// index (elem bits 3..5). Bijective per row; writes and reads use the same
// involution. 8B accesses at 4-aligned col stay within one granule.
// Verified r4/r5: correct (passed), conflicts 8.3M -> 2.5M.
__device__ __forceinline__ int sw(int row, int col) {
  return row * 64 + (col ^ ((row & 7) << 3));
}

// ---------------------------------------------------------------- cvt_q
__global__ __launch_bounds__(256) void cvt_q(const float* __restrict__ Q,
                                             unsigned short* __restrict__ Qbf) {
  size_t i = (size_t)blockIdx.x * 256 + threadIdx.x;
  float4 v = ((const float4*)Q)[i];
  u16x4 o;
  o[0] = f2bf(v.x); o[1] = f2bf(v.y); o[2] = f2bf(v.z); o[3] = f2bf(v.w);
  ((u16x4*)Qbf)[i] = o;
}

// ---------------------------------------------------------------- cvt_wt
__global__ __launch_bounds__(256) void cvt_wt(const float* __restrict__ Wq,
                                              const float* __restrict__ Wk,
                                              const float* __restrict__ Wv,
                                              unsigned short* __restrict__ WT) {
  const int z = blockIdx.z;
  const float* W = (z == 0) ? Wq : (z == 1) ? Wk : Wv;
  __shared__ float tile[32][33];
  const int k0 = blockIdx.y * 32, n0 = blockIdx.x * 32;
  const int tx = threadIdx.x & 31, ty = threadIdx.x >> 5;
  for (int i = 0; i < 4; ++i)
    tile[ty + i * 8][tx] = W[(size_t)(k0 + ty + i * 8) * D_MODEL + n0 + tx];
  __syncthreads();
  unsigned short* out = WT + (size_t)z * D_MODEL * D_MODEL;
  for (int i = 0; i < 4; ++i)
    out[(size_t)(n0 + ty + i * 8) * D_MODEL + k0 + tx] = f2bf(tile[tx][ty + i * 8]);
}

// ---------------------------------------------------------------- gemm_qkv
// (unchanged from round 3 -- verified: fused M=8192 x N=3072, BK=64 dbuf,
//  counted vmcnt(8), T2 swizzle, XCD-bijective m-outer block swizzle)
#define GQ_BM 128
#define GQ_BN 128
#define GQ_BK 64
#define GQ_NT (D_MODEL / GQ_BK)   // 16

__global__ __launch_bounds__(256, 2) void gemm_qkv(
    const unsigned short* __restrict__ Qbf,
    const unsigned short* __restrict__ WT,
    const float* __restrict__ bq_p, const float* __restrict__ bk_p,
    const float* __restrict__ bv_p,
    float* __restrict__ out_qa,
    unsigned short* __restrict__ kbf,
    unsigned short* __restrict__ vt) {
  const int f   = blockIdx.x;                 // 0..1535
  const int swz = (f & 7) * 192 + (f >> 3);   // XCD-bijective (1536%8==0)
  const int mm  = swz / 24;                   // 0..63  (m-outer)
  const int nn  = swz % 24;                   // 0..23
  const int m0  = mm * GQ_BM;
  const int n0g = nn * GQ_BN;                 // global col in [0,3072)
  const int z   = n0g >> 10;                  // block-uniform (1024%128==0)
  const int n0  = n0g & 1023;

  __shared__ unsigned short smA[2][GQ_BM * GQ_BK];  // 16 KB each
  __shared__ unsigned short smB[2][GQ_BN * GQ_BK];  // total 64 KB

  const int t    = threadIdx.x;
  const int lane = t & 63;
  const int w    = t >> 6;
  const int quad = lane >> 4;
  const int l16  = lane & 15;
  const int wr   = w >> 1, wc = w & 1;

  f32x4 acc[4][4];
  for (int i = 0; i < 4; ++i)
    for (int j = 0; j < 4; ++j) acc[i][j] = (f32x4){0.f, 0.f, 0.f, 0.f};

  auto stage = [&](int p, int kt) {
    #pragma unroll
    for (int r = 0; r < 4; ++r) {
      int o   = (r * 256 + t) * 8;                 // elem offset in [0,8192)
      int row = o >> 6;                            // tile row 0..127
      int col = (o & 63) ^ ((row & 7) << 3);       // pre-swizzled k-col
      const unsigned short* ga = Qbf + (size_t)(m0 + row)  * D_MODEL + kt * 64 + col;
      const unsigned short* gb = WT  + (size_t)(n0g + row) * D_MODEL + kt * 64 + col;
      __builtin_amdgcn_global_load_lds(
          (const __attribute__((address_space(1))) void*)ga,
          (__attribute__((address_space(3))) void*)&smA[p][o], 16, 0, 0);
      __builtin_amdgcn_global_load_lds(
          (const __attribute__((address_space(1))) void*)gb,
          (__attribute__((address_space(3))) void*)&smB[p][o], 16, 0, 0);
    }
  };

  stage(0, 0);
  stage(1, 1);
  asm volatile("s_waitcnt vmcnt(8)" ::: "memory");
  __builtin_amdgcn_s_barrier();
  asm volatile("" ::: "memory");

  for (int kt = 0; kt < GQ_NT; ++kt) {
    const int p = kt & 1;

    short8 af[4][2], bf[4][2];
    #pragma unroll
    for (int mi = 0; mi < 4; ++mi) {
      int row = wr * 64 + mi * 16 + l16;
      #pragma unroll
      for (int kk = 0; kk < 2; ++kk)
        af[mi][kk] = *(const short8*)
            &smA[p][(row * 64 + kk * 32 + quad * 8) ^ ((row & 7) << 3)];
    }
    #pragma unroll
    for (int ni = 0; ni < 4; ++ni) {
      int row = wc * 64 + ni * 16 + l16;
      #pragma unroll
      for (int kk = 0; kk < 2; ++kk)
        bf[ni][kk] = *(const short8*)
            &smB[p][(row * 64 + kk * 32 + quad * 8) ^ ((row & 7) << 3)];
    }

    __builtin_amdgcn_s_setprio(1);
    #pragma unroll
    for (int mi = 0; mi < 4; ++mi)
      #pragma unroll
      for (int ni = 0; ni < 4; ++ni) {
        acc[mi][ni] = __builtin_amdgcn_mfma_f32_16x16x32_bf16(
            af[mi][0], bf[ni][0], acc[mi][ni], 0, 0, 0);
        acc[mi][ni] = __builtin_amdgcn_mfma_f32_16x16x32_bf16(
            af[mi][1], bf[ni][1], acc[mi][ni], 0, 0, 0);
      }
    __builtin_amdgcn_s_setprio(0);

    __builtin_amdgcn_s_barrier();            // everyone done reading buf p
    asm volatile("" ::: "memory");
    if (kt + 2 < GQ_NT) {
      stage(p, kt + 2);                      // refill vacated buffer
      asm volatile("s_waitcnt vmcnt(8)" ::: "memory");   // tile kt+1 landed
    } else {
      asm volatile("s_waitcnt vmcnt(0)" ::: "memory");   // drain at the end
    }
    __builtin_amdgcn_s_barrier();            // tile kt+1 visible to all
    asm volatile("" ::: "memory");
  }

  const float* bias = (z == 0) ? bq_p : (z == 1) ? bk_p : bv_p;
  if (z == 2) {
    for (int ni = 0; ni < 4; ++ni) {
      int n = n0 + wc * 64 + ni * 16 + l16;
      float bval = bias[n];
      int h = n >> 6, d = n & 63;
      for (int mi = 0; mi < 4; ++mi) {
        int m = m0 + wr * 64 + mi * 16 + quad * 4;
        int b = m >> 11, s = m & 2047;
        u16x4 o;
        for (int j = 0; j < 4; ++j) o[j] = f2bf(acc[mi][ni][j] + bval);
        *(u16x4*)&vt[(size_t)((b * 16 + h) * 64 + d) * SEQ + s] = o;
      }
    }
  } else {
    for (int ni = 0; ni < 4; ++ni) {
      int n = n0 + wc * 64 + ni * 16 + l16;
      float bval = bias[n];
      for (int mi = 0; mi < 4; ++mi) {
        int mbase = m0 + wr * 64 + mi * 16 + quad * 4;
        for (int j = 0; j < 4; ++j) {
          float v = acc[mi][ni][j] + bval;
          size_t idx = (size_t)(mbase + j) * D_MODEL + n;
          if (z == 0) out_qa[idx] = v;
          else        kbf[idx] = f2bf(v);
        }
      }
    }
  }
}

// ---------------------------------------------------------------- attn
// Round-3 structure EXACTLY (verified 80.6 us): 256 thr = 4 waves; wave
// owns TWO 16-q groups of the 128-q tile (kf/vf fragment reads shared
// across groups); reg-prefetch K/V staging through LDS; 2 barriers/tile;
// sP aliases sQ. ONLY change vs r3: LDS layout PST=72 padded -> swizzled
// [R][64] via sw() (verified correct + conflicts 8.3M->2.5M in r4).
#define QBLK 128

__global__ __launch_bounds__(256, 4) void attn(
    const float* __restrict__ qa,            // [8192,1024] fp32
    const unsigned short* __restrict__ kbf,  // [8192,1024] bf16
    const unsigned short* __restrict__ vt,   // [(bh)*64+d][2048] bf16 (V^T)
    const int* __restrict__ length,
    float* __restrict__ ctx) {               // [8192,1024] fp32
  const int flat = blockIdx.y * 16 + blockIdx.x;          // 0..1023
  const int low = flat & 3;
  const int mid = (flat >> 2) & 15;
  const int hi  = flat >> 6;                              // 0..15
  const int b  = (low + mid + (mid >> 2) + hi + (hi >> 2)) & 3;
  const int h  = mid;
  const int qt = hi;                                      // 128-q tile index
  const int bh = b * 16 + h;
  const int len = length[b];

  const int t    = threadIdx.x;
  const int lane = t & 63;
  const int w    = t >> 6;              // 0..3
  const int quad = lane >> 4;
  const int l16  = lane & 15;
  const int r8   = t >> 3;              // 0..31
  const int c8   = (t & 7) * 8;         // 0,8,..,56

  __shared__ unsigned short sQP[QBLK * 64];  // [q][64] swizzled; Q then P
  __shared__ unsigned short sK[64 * 64];     // [k][64] swizzled
  __shared__ unsigned short sVT[64 * 64];    // [d][64] swizzled
  unsigned short* const sP = sQP;            // alias (Q consumed first)

  const float SCL = 0.125f * 1.44269504f;   // 1/sqrt(64) * log2(e)

  // stage Q tile (fp32 -> bf16, pre-scaled): 128 rows x 64 d
  for (int half = 0; half < 4; ++half) {
    int r = r8 + half * 32;
    const float* src = qa + (size_t)(b * SEQ + qt * QBLK + r) * D_MODEL + h * D_KH + c8;
    float4 v0 = *(const float4*)src;
    float4 v1 = *(const float4*)(src + 4);
    short8 o;
    o[0] = (short)f2bf(v0.x * SCL); o[1] = (short)f2bf(v0.y * SCL);
    o[2] = (short)f2bf(v0.z * SCL); o[3] = (short)f2bf(v0.w * SCL);
    o[4] = (short)f2bf(v1.x * SCL); o[5] = (short)f2bf(v1.y * SCL);
    o[6] = (short)f2bf(v1.z * SCL); o[7] = (short)f2bf(v1.w * SCL);
    *(short8*)&sQP[sw(r, c8)] = o;
  }
  __syncthreads();

  const int qr0 = w * 16 + l16;
  const int qr1 = 64 + qr0;
  short8 qf00 = *(const short8*)&sQP[sw(qr0, quad * 8)];
  short8 qf01 = *(const short8*)&sQP[sw(qr0, 32 + quad * 8)];
  short8 qf10 = *(const short8*)&sQP[sw(qr1, quad * 8)];
  short8 qf11 = *(const short8*)&sQP[sw(qr1, 32 + quad * 8)];

  f32x4 acc0[4], acc1[4];
  for (int i = 0; i < 4; ++i) {
    acc0[i] = (f32x4){0.f, 0.f, 0.f, 0.f};
    acc1[i] = (f32x4){0.f, 0.f, 0.f, 0.f};
  }
  float den0 = 0.f, den1 = 0.f;

  const unsigned short* kbase_p = kbf + (size_t)b * SEQ * D_MODEL + h * D_KH;
  const unsigned short* vbase_p = vt + (size_t)bh * 64 * SEQ;

  const int nkt = (len + 63) >> 6;

  short8 rk[2], rv[2];
  for (int half = 0; half < 2; ++half) {
    int r = r8 + half * 32;
    rk[half] = *(const short8*)(kbase_p + (size_t)r * D_MODEL + c8);
    rv[half] = *(const short8*)(vbase_p + (size_t)r * SEQ + c8);
  }

  for (int kt = 0; kt < nkt; ++kt) {
    __syncthreads();   // prev-iter readers done (covers qf reads on kt=0)
    for (int half = 0; half < 2; ++half) {
      int r = r8 + half * 32;
      *(short8*)&sK[sw(r, c8)]  = rk[half];
      *(short8*)&sVT[sw(r, c8)] = rv[half];
    }
    __syncthreads();   // staging visible

    if (kt + 1 < nkt) {
      for (int half = 0; half < 2; ++half) {
        int r = r8 + half * 32;
        rk[half] = *(const short8*)(kbase_p + (size_t)((kt + 1) * 64 + r) * D_MODEL + c8);
        rv[half] = *(const short8*)(vbase_p + (size_t)r * SEQ + (kt + 1) * 64 + c8);
      }
    }

    const bool full = ((kt + 1) << 6) <= len;   // block-uniform

    // S^T = K.Q^T for both q-groups; kf reads shared.
    for (int n = 0; n < 4; ++n) {
      short8 kf0 = *(const short8*)&sK[sw(n * 16 + l16, quad * 8)];
      short8 kf1 = *(const short8*)&sK[sw(n * 16 + l16, 32 + quad * 8)];
      f32x4 s0 = (f32x4){0.f, 0.f, 0.f, 0.f};
      s0 = __builtin_amdgcn_mfma_f32_16x16x32_bf16(kf0, qf00, s0, 0, 0, 0);
      s0 = __builtin_amdgcn_mfma_f32_16x16x32_bf16(kf1, qf01, s0, 0, 0, 0);
      f32x4 s1 = (f32x4){0.f, 0.f, 0.f, 0.f};
      s1 = __builtin_amdgcn_mfma_f32_16x16x32_bf16(kf0, qf10, s1, 0, 0, 0);
      s1 = __builtin_amdgcn_mfma_f32_16x16x32_bf16(kf1, qf11, s1, 0, 0, 0);

      float e0, e1, e2, e3, f0, f1, f2, f3;
      if (full) {
        e0 = exp2f(s0[0]); e1 = exp2f(s0[1]); e2 = exp2f(s0[2]); e3 = exp2f(s0[3]);
        f0 = exp2f(s1[0]); f1 = exp2f(s1[1]); f2 = exp2f(s1[2]); f3 = exp2f(s1[3]);
      } else {
        int kb = kt * 64 + n * 16 + quad * 4;
        e0 = (kb + 0 < len) ? exp2f(s0[0]) : 0.f;
        e1 = (kb + 1 < len) ? exp2f(s0[1]) : 0.f;
        e2 = (kb + 2 < len) ? exp2f(s0[2]) : 0.f;
        e3 = (kb + 3 < len) ? exp2f(s0[3]) : 0.f;
        f0 = (kb + 0 < len) ? exp2f(s1[0]) : 0.f;
        f1 = (kb + 1 < len) ? exp2f(s1[1]) : 0.f;
        f2 = (kb + 2 < len) ? exp2f(s1[2]) : 0.f;
        f3 = (kb + 3 < len) ? exp2f(s1[3]) : 0.f;
      }
      den0 += (e0 + e1) + (e2 + e3);
      den1 += (f0 + f1) + (f2 + f3);
      u32x2 pk;
      pk[0] = __builtin_amdgcn_perm(fbits(e1), fbits(e0), 0x07060302);
      pk[1] = __builtin_amdgcn_perm(fbits(e3), fbits(e2), 0x07060302);
      *(u32x2*)&sP[sw(qr0, n * 16 + quad * 4)] = pk;
      u32x2 pk1;
      pk1[0] = __builtin_amdgcn_perm(fbits(f1), fbits(f0), 0x07060302);
      pk1[1] = __builtin_amdgcn_perm(fbits(f3), fbits(f2), 0x07060302);
      *(u32x2*)&sP[sw(qr1, n * 16 + quad * 4)] = pk1;
    }
    // sP rows are per-wave -> no barrier before PV

    short8 pf00 = *(const short8*)&sP[sw(qr0, quad * 8)];
    short8 pf01 = *(const short8*)&sP[sw(qr0, 32 + quad * 8)];
    short8 pf10 = *(const short8*)&sP[sw(qr1, quad * 8)];
    short8 pf11 = *(const short8*)&sP[sw(qr1, 32 + quad * 8)];
    for (int n2 = 0; n2 < 4; ++n2) {
      short8 vf0 = *(const short8*)&sVT[sw(n2 * 16 + l16, quad * 8)];
      short8 vf1 = *(const short8*)&sVT[sw(n2 * 16 + l16, 32 + quad * 8)];
      acc0[n2] = __builtin_amdgcn_mfma_f32_16x16x32_bf16(vf0, pf00, acc0[n2], 0, 0, 0);
      acc0[n2] = __builtin_amdgcn_mfma_f32_16x16x32_bf16(vf1, pf01, acc0[n2], 0, 0, 0);
      acc1[n2] = __builtin_amdgcn_mfma_f32_16x16x32_bf16(vf0, pf10, acc1[n2], 0, 0, 0);
      acc1[n2] = __builtin_amdgcn_mfma_f32_16x16x32_bf16(vf1, pf11, acc1[n2], 0, 0, 0);
    }
  }

  den0 += __shfl_xor(den0, 16, 64);
  den0 += __shfl_xor(den0, 32, 64);
  den1 += __shfl_xor(den1, 16, 64);
  den1 += __shfl_xor(den1, 32, 64);
  float inv0 = 1.f / (den0 + 1e-8f);
  float inv1 = 1.f / (den1 + 1e-8f);

  {
    int q0 = qt * QBLK + w * 16 + l16;
    float* dst0 = ctx + (size_t)(b * SEQ + q0) * D_MODEL + h * D_KH;
    float* dst1 = dst0 + (size_t)64 * D_MODEL;   // q0 + 64
    for (int n2 = 0; n2 < 4; ++n2) {
      f32x4 o0 = acc0[n2];
      f32x4 o1 = acc1[n2];
      *(float4*)(dst0 + n2 * 16 + quad * 4) =
          make_float4(o0[0] * inv0, o0[1] * inv0, o0[2] * inv0, o0[3] * inv0);
      *(float4*)(dst1 + n2 * 16 + quad * 4) =
          make_float4(o1[0] * inv1, o1[1] * inv1, o1[2] * inv1, o1[3] * inv1);
    }
  }
}

// ---------------------------------------------------------------- launch
extern "C" void kernel_launch(void* const* d_in, const int* in_sizes, int n_in,
                              void* d_out, int out_size, void* d_ws, size_t ws_size,
                              hipStream_t stream) {
  const float* Q      = (const float*)d_in[0];
  const int*   length = (const int*)d_in[1];
  const float* Wq     = (const float*)d_in[2];
  const float* bq     = (const float*)d_in[3];
  const float* Wk     = (const float*)d_in[4];
  const float* bk     = (const float*)d_in[5];
  const float* Wv     = (const float*)d_in[6];
  const float* bv     = (const float*)d_in[7];

  float* out_ctx = (float*)d_out;                         // [8192,1024]
  float* out_qa  = out_ctx + (size_t)M_TOTAL * D_MODEL;   // [8192,1024]

  char* ws = (char*)d_ws;
  unsigned short* Qbf = (unsigned short*)ws;                              // 16 MB
  unsigned short* WT  = (unsigned short*)(ws + (size_t)16 * 1024 * 1024); //  6 MB
  unsigned short* Kbf = (unsigned short*)(ws + (size_t)22 * 1024 * 1024); // 16 MB
  unsigned short* Vt  = (unsigned short*)(ws + (size_t)38 * 1024 * 1024); // 16 MB

  hipLaunchKernelGGL(cvt_q, dim3((M_TOTAL * D_MODEL) / (256 * 4)), dim3(256), 0, stream,
                     Q, Qbf);
  hipLaunchKernelGGL(cvt_wt, dim3(32, 32, 3), dim3(256), 0, stream, Wq, Wk, Wv, WT);
  hipLaunchKernelGGL(gemm_qkv, dim3(64 * 24), dim3(256), 0, stream,
                     Qbf, WT, bq, bk, bv, out_qa, Kbf, Vt);
  hipLaunchKernelGGL(attn, dim3(SEQ / QBLK, BATCH * N_HEADS), dim3(256), 0, stream,
                     out_qa, Kbf, Vt, length, out_ctx);
}

// Round 7
// 241.379 us; speedup vs baseline: 1.2706x; 1.1810x over previous
//
#include <hip/hip_runtime.h>

#define D_MODEL 1024
#define N_HEADS 16
#define D_KH    64
#define BATCH   4
#define SEQ     2048
#define M_TOTAL (BATCH*SEQ)   // 8192

typedef __attribute__((ext_vector_type(8))) short short8;
typedef __attribute__((ext_vector_type(4))) float f32x4;
typedef __attribute__((ext_vector_type(4))) unsigned short u16x4;
typedef __attribute__((ext_vector_type(2))) unsigned int u32x2;

__device__ __forceinline__ unsigned short f2bf(float f) {
  union { float f; unsigned u; } v; v.f = f;
  unsigned r = v.u + 0x7FFFu + ((v.u >> 16) & 1u);
  return (unsigned short)(r >> 16);
}
__device__ __forceinline__ unsigned fbits(float f) {
  union { float f; unsigned u; } v; v.f = f; return v.u;
}

// ---------------------------------------------------------------- cvt_all
// cvt_q and cvt_wt fused into ONE launch (block-uniform branch on flat
// block id). Part codes identical to the verified separate kernels;
// saves one kernel-launch gap in the serial 4-kernel chain.
//   blocks [0, 8192)        : Q fp32 -> bf16 (float4/u16x4 vectorized)
//   blocks [8192, 8192+3072): W transpose+cvt, 32x32 LDS tiles
__global__ __launch_bounds__(256) void cvt_all(
    const float* __restrict__ Q, unsigned short* __restrict__ Qbf,
    const float* __restrict__ Wq, const float* __restrict__ Wk,
    const float* __restrict__ Wv, unsigned short* __restrict__ WT) {
  __shared__ float tile[32][33];
  const int bid = blockIdx.x;
  if (bid < 8192) {
    size_t i = (size_t)bid * 256 + threadIdx.x;
    float4 v = ((const float4*)Q)[i];
    u16x4 o;
    o[0] = f2bf(v.x); o[1] = f2bf(v.y); o[2] = f2bf(v.z); o[3] = f2bf(v.w);
    ((u16x4*)Qbf)[i] = o;
  } else {
    const int r = bid - 8192;
    const int z = r >> 10;                 // 0..2
    const int rem = r & 1023;
    const int k0 = (rem >> 5) * 32, n0 = (rem & 31) * 32;
    const float* W = (z == 0) ? Wq : (z == 1) ? Wk : Wv;
    const int tx = threadIdx.x & 31, ty = threadIdx.x >> 5;
    for (int i = 0; i < 4; ++i)
      tile[ty + i * 8][tx] = W[(size_t)(k0 + ty + i * 8) * D_MODEL + n0 + tx];
    __syncthreads();
    unsigned short* out = WT + (size_t)z * D_MODEL * D_MODEL;
    for (int i = 0; i < 4; ++i)
      out[(size_t)(n0 + ty + i * 8) * D_MODEL + k0 + tx] = f2bf(tile[tx][ty + i * 8]);
  }
}

// ---------------------------------------------------------------- gemm_qkv
// (byte-exact round 3 -- verified: fused M=8192 x N=3072, BK=64 dbuf,
//  counted vmcnt(8), T2 swizzle, XCD-bijective m-outer block swizzle)
#define GQ_BM 128
#define GQ_BN 128
#define GQ_BK 64
#define GQ_NT (D_MODEL / GQ_BK)   // 16

__global__ __launch_bounds__(256, 2) void gemm_qkv(
    const unsigned short* __restrict__ Qbf,
    const unsigned short* __restrict__ WT,
    const float* __restrict__ bq_p, const float* __restrict__ bk_p,
    const float* __restrict__ bv_p,
    float* __restrict__ out_qa,
    unsigned short* __restrict__ kbf,
    unsigned short* __restrict__ vt) {
  const int f   = blockIdx.x;                 // 0..1535
  const int swz = (f & 7) * 192 + (f >> 3);   // XCD-bijective (1536%8==0)
  const int mm  = swz / 24;                   // 0..63  (m-outer)
  const int nn  = swz % 24;                   // 0..23
  const int m0  = mm * GQ_BM;
  const int n0g = nn * GQ_BN;                 // global col in [0,3072)
  const int z   = n0g >> 10;                  // block-uniform (1024%128==0)
  const int n0  = n0g & 1023;

  __shared__ unsigned short smA[2][GQ_BM * GQ_BK];  // 16 KB each
  __shared__ unsigned short smB[2][GQ_BN * GQ_BK];  // total 64 KB

  const int t    = threadIdx.x;
  const int lane = t & 63;
  const int w    = t >> 6;
  const int quad = lane >> 4;
  const int l16  = lane & 15;
  const int wr   = w >> 1, wc = w & 1;

  f32x4 acc[4][4];
  for (int i = 0; i < 4; ++i)
    for (int j = 0; j < 4; ++j) acc[i][j] = (f32x4){0.f, 0.f, 0.f, 0.f};

  auto stage = [&](int p, int kt) {
    #pragma unroll
    for (int r = 0; r < 4; ++r) {
      int o   = (r * 256 + t) * 8;                 // elem offset in [0,8192)
      int row = o >> 6;                            // tile row 0..127
      int col = (o & 63) ^ ((row & 7) << 3);       // pre-swizzled k-col
      const unsigned short* ga = Qbf + (size_t)(m0 + row)  * D_MODEL + kt * 64 + col;
      const unsigned short* gb = WT  + (size_t)(n0g + row) * D_MODEL + kt * 64 + col;
      __builtin_amdgcn_global_load_lds(
          (const __attribute__((address_space(1))) void*)ga,
          (__attribute__((address_space(3))) void*)&smA[p][o], 16, 0, 0);
      __builtin_amdgcn_global_load_lds(
          (const __attribute__((address_space(1))) void*)gb,
          (__attribute__((address_space(3))) void*)&smB[p][o], 16, 0, 0);
    }
  };

  stage(0, 0);
  stage(1, 1);
  asm volatile("s_waitcnt vmcnt(8)" ::: "memory");
  __builtin_amdgcn_s_barrier();
  asm volatile("" ::: "memory");

  for (int kt = 0; kt < GQ_NT; ++kt) {
    const int p = kt & 1;

    short8 af[4][2], bf[4][2];
    #pragma unroll
    for (int mi = 0; mi < 4; ++mi) {
      int row = wr * 64 + mi * 16 + l16;
      #pragma unroll
      for (int kk = 0; kk < 2; ++kk)
        af[mi][kk] = *(const short8*)
            &smA[p][(row * 64 + kk * 32 + quad * 8) ^ ((row & 7) << 3)];
    }
    #pragma unroll
    for (int ni = 0; ni < 4; ++ni) {
      int row = wc * 64 + ni * 16 + l16;
      #pragma unroll
      for (int kk = 0; kk < 2; ++kk)
        bf[ni][kk] = *(const short8*)
            &smB[p][(row * 64 + kk * 32 + quad * 8) ^ ((row & 7) << 3)];
    }

    __builtin_amdgcn_s_setprio(1);
    #pragma unroll
    for (int mi = 0; mi < 4; ++mi)
      #pragma unroll
      for (int ni = 0; ni < 4; ++ni) {
        acc[mi][ni] = __builtin_amdgcn_mfma_f32_16x16x32_bf16(
            af[mi][0], bf[ni][0], acc[mi][ni], 0, 0, 0);
        acc[mi][ni] = __builtin_amdgcn_mfma_f32_16x16x32_bf16(
            af[mi][1], bf[ni][1], acc[mi][ni], 0, 0, 0);
      }
    __builtin_amdgcn_s_setprio(0);

    __builtin_amdgcn_s_barrier();            // everyone done reading buf p
    asm volatile("" ::: "memory");
    if (kt + 2 < GQ_NT) {
      stage(p, kt + 2);                      // refill vacated buffer
      asm volatile("s_waitcnt vmcnt(8)" ::: "memory");   // tile kt+1 landed
    } else {
      asm volatile("s_waitcnt vmcnt(0)" ::: "memory");   // drain at the end
    }
    __builtin_amdgcn_s_barrier();            // tile kt+1 visible to all
    asm volatile("" ::: "memory");
  }

  const float* bias = (z == 0) ? bq_p : (z == 1) ? bk_p : bv_p;
  if (z == 2) {
    for (int ni = 0; ni < 4; ++ni) {
      int n = n0 + wc * 64 + ni * 16 + l16;
      float bval = bias[n];
      int h = n >> 6, d = n & 63;
      for (int mi = 0; mi < 4; ++mi) {
        int m = m0 + wr * 64 + mi * 16 + quad * 4;
        int b = m >> 11, s = m & 2047;
        u16x4 o;
        for (int j = 0; j < 4; ++j) o[j] = f2bf(acc[mi][ni][j] + bval);
        *(u16x4*)&vt[(size_t)((b * 16 + h) * 64 + d) * SEQ + s] = o;
      }
    }
  } else {
    for (int ni = 0; ni < 4; ++ni) {
      int n = n0 + wc * 64 + ni * 16 + l16;
      float bval = bias[n];
      for (int mi = 0; mi < 4; ++mi) {
        int mbase = m0 + wr * 64 + mi * 16 + quad * 4;
        for (int j = 0; j < 4; ++j) {
          float v = acc[mi][ni][j] + bval;
          size_t idx = (size_t)(mbase + j) * D_MODEL + n;
          if (z == 0) out_qa[idx] = v;
          else        kbf[idx] = f2bf(v);
        }
      }
    }
  }
}

// ---------------------------------------------------------------- attn
// BYTE-EXACT round 3 (verified 80.6 us steady): 256 thr = 4 waves; wave
// owns TWO 16-q groups of the 128-q tile (kf/vf fragment reads shared
// across groups); reg-prefetch K/V staging through LDS (PST=72 padded
// rows); 2 barriers/tile; sP aliases sQ. NOTE (r6 lesson): the XOR-
// swizzle variant reduced bank conflicts 8.3M->2.4M but regressed 50%
// (compiler regalloc -> scratch); conflicts are NOT on this structure's
// critical path. Do not re-attempt LDS layout changes here without disasm.
#define PST 72   // LDS row stride (elements)
#define QBLK 128

__global__ __launch_bounds__(256, 4) void attn(
    const float* __restrict__ qa,            // [8192,1024] fp32
    const unsigned short* __restrict__ kbf,  // [8192,1024] bf16
    const unsigned short* __restrict__ vt,   // [(bh)*64+d][2048] bf16 (V^T)
    const int* __restrict__ length,
    float* __restrict__ ctx) {               // [8192,1024] fp32
  const int flat = blockIdx.y * 16 + blockIdx.x;          // 0..1023
  const int low = flat & 3;
  const int mid = (flat >> 2) & 15;
  const int hi  = flat >> 6;                              // 0..15
  const int b  = (low + mid + (mid >> 2) + hi + (hi >> 2)) & 3;
  const int h  = mid;
  const int qt = hi;                                      // 128-q tile index
  const int bh = b * 16 + h;
  const int len = length[b];

  const int t    = threadIdx.x;
  const int lane = t & 63;
  const int w    = t >> 6;              // 0..3
  const int quad = lane >> 4;
  const int l16  = lane & 15;
  const int r8   = t >> 3;              // 0..31
  const int c8   = (t & 7) * 8;         // 0,8,..,56

  __shared__ unsigned short sQ[QBLK * PST];  // [q][d] pre-scaled; reused as sP
  __shared__ unsigned short sK[64 * PST];    // [k][d]
  __shared__ unsigned short sVT[64 * PST];   // [d][k]
  unsigned short* const sP = sQ;             // [q][k] alias

  const float SCL = 0.125f * 1.44269504f;   // 1/sqrt(64) * log2(e)

  // stage Q tile (fp32 -> bf16, pre-scaled): 128 rows x 64 d
  for (int half = 0; half < 4; ++half) {
    int r = r8 + half * 32;
    const float* src = qa + (size_t)(b * SEQ + qt * QBLK + r) * D_MODEL + h * D_KH + c8;
    float4 v0 = *(const float4*)src;
    float4 v1 = *(const float4*)(src + 4);
    short8 o;
    o[0] = (short)f2bf(v0.x * SCL); o[1] = (short)f2bf(v0.y * SCL);
    o[2] = (short)f2bf(v0.z * SCL); o[3] = (short)f2bf(v0.w * SCL);
    o[4] = (short)f2bf(v1.x * SCL); o[5] = (short)f2bf(v1.y * SCL);
    o[6] = (short)f2bf(v1.z * SCL); o[7] = (short)f2bf(v1.w * SCL);
    *(short8*)&sQ[r * PST + c8] = o;
  }
  __syncthreads();

  const int qr0 = w * 16 + l16;
  const int qr1 = 64 + qr0;
  short8 qf00 = *(const short8*)&sQ[qr0 * PST + quad * 8];
  short8 qf01 = *(const short8*)&sQ[qr0 * PST + 32 + quad * 8];
  short8 qf10 = *(const short8*)&sQ[qr1 * PST + quad * 8];
  short8 qf11 = *(const short8*)&sQ[qr1 * PST + 32 + quad * 8];

  f32x4 acc0[4], acc1[4];
  for (int i = 0; i < 4; ++i) {
    acc0[i] = (f32x4){0.f, 0.f, 0.f, 0.f};
    acc1[i] = (f32x4){0.f, 0.f, 0.f, 0.f};
  }
  float den0 = 0.f, den1 = 0.f;

  const unsigned short* kbase_p = kbf + (size_t)b * SEQ * D_MODEL + h * D_KH;
  const unsigned short* vbase_p = vt + (size_t)bh * 64 * SEQ;

  const int nkt = (len + 63) >> 6;

  short8 rk[2], rv[2];
  for (int half = 0; half < 2; ++half) {
    int r = r8 + half * 32;
    rk[half] = *(const short8*)(kbase_p + (size_t)r * D_MODEL + c8);
    rv[half] = *(const short8*)(vbase_p + (size_t)r * SEQ + c8);
  }

  for (int kt = 0; kt < nkt; ++kt) {
    __syncthreads();   // prev-iter readers done (covers qf reads on kt=0)
    for (int half = 0; half < 2; ++half) {
      int r = r8 + half * 32;
      *(short8*)&sK[r * PST + c8]  = rk[half];
      *(short8*)&sVT[r * PST + c8] = rv[half];
    }
    __syncthreads();   // staging visible

    if (kt + 1 < nkt) {
      for (int half = 0; half < 2; ++half) {
        int r = r8 + half * 32;
        rk[half] = *(const short8*)(kbase_p + (size_t)((kt + 1) * 64 + r) * D_MODEL + c8);
        rv[half] = *(const short8*)(vbase_p + (size_t)r * SEQ + (kt + 1) * 64 + c8);
      }
    }

    const bool full = ((kt + 1) << 6) <= len;   // block-uniform

    // S^T = K.Q^T for both q-groups; kf reads shared.
    for (int n = 0; n < 4; ++n) {
      short8 kf0 = *(const short8*)&sK[(n * 16 + l16) * PST + quad * 8];
      short8 kf1 = *(const short8*)&sK[(n * 16 + l16) * PST + 32 + quad * 8];
      f32x4 s0 = (f32x4){0.f, 0.f, 0.f, 0.f};
      s0 = __builtin_amdgcn_mfma_f32_16x16x32_bf16(kf0, qf00, s0, 0, 0, 0);
      s0 = __builtin_amdgcn_mfma_f32_16x16x32_bf16(kf1, qf01, s0, 0, 0, 0);
      f32x4 s1 = (f32x4){0.f, 0.f, 0.f, 0.f};
      s1 = __builtin_amdgcn_mfma_f32_16x16x32_bf16(kf0, qf10, s1, 0, 0, 0);
      s1 = __builtin_amdgcn_mfma_f32_16x16x32_bf16(kf1, qf11, s1, 0, 0, 0);

      float e0, e1, e2, e3, f0, f1, f2, f3;
      if (full) {
        e0 = exp2f(s0[0]); e1 = exp2f(s0[1]); e2 = exp2f(s0[2]); e3 = exp2f(s0[3]);
        f0 = exp2f(s1[0]); f1 = exp2f(s1[1]); f2 = exp2f(s1[2]); f3 = exp2f(s1[3]);
      } else {
        int kb = kt * 64 + n * 16 + quad * 4;
        e0 = (kb + 0 < len) ? exp2f(s0[0]) : 0.f;
        e1 = (kb + 1 < len) ? exp2f(s0[1]) : 0.f;
        e2 = (kb + 2 < len) ? exp2f(s0[2]) : 0.f;
        e3 = (kb + 3 < len) ? exp2f(s0[3]) : 0.f;
        f0 = (kb + 0 < len) ? exp2f(s1[0]) : 0.f;
        f1 = (kb + 1 < len) ? exp2f(s1[1]) : 0.f;
        f2 = (kb + 2 < len) ? exp2f(s1[2]) : 0.f;
        f3 = (kb + 3 < len) ? exp2f(s1[3]) : 0.f;
      }
      den0 += (e0 + e1) + (e2 + e3);
      den1 += (f0 + f1) + (f2 + f3);
      u32x2 pk;
      pk[0] = __builtin_amdgcn_perm(fbits(e1), fbits(e0), 0x07060302);
      pk[1] = __builtin_amdgcn_perm(fbits(e3), fbits(e2), 0x07060302);
      *(u32x2*)&sP[qr0 * PST + n * 16 + quad * 4] = pk;
      u32x2 pk1;
      pk1[0] = __builtin_amdgcn_perm(fbits(f1), fbits(f0), 0x07060302);
      pk1[1] = __builtin_amdgcn_perm(fbits(f3), fbits(f2), 0x07060302);
      *(u32x2*)&sP[qr1 * PST + n * 16 + quad * 4] = pk1;
    }
    // sP rows are per-wave -> no barrier before PV

    short8 pf00 = *(const short8*)&sP[qr0 * PST + quad * 8];
    short8 pf01 = *(const short8*)&sP[qr0 * PST + 32 + quad * 8];
    short8 pf10 = *(const short8*)&sP[qr1 * PST + quad * 8];
    short8 pf11 = *(const short8*)&sP[qr1 * PST + 32 + quad * 8];
    for (int n2 = 0; n2 < 4; ++n2) {
      short8 vf0 = *(const short8*)&sVT[(n2 * 16 + l16) * PST + quad * 8];
      short8 vf1 = *(const short8*)&sVT[(n2 * 16 + l16) * PST + 32 + quad * 8];
      acc0[n2] = __builtin_amdgcn_mfma_f32_16x16x32_bf16(vf0, pf00, acc0[n2], 0, 0, 0);
      acc0[n2] = __builtin_amdgcn_mfma_f32_16x16x32_bf16(vf1, pf01, acc0[n2], 0, 0, 0);
      acc1[n2] = __builtin_amdgcn_mfma_f32_16x16x32_bf16(vf0, pf10, acc1[n2], 0, 0, 0);
      acc1[n2] = __builtin_amdgcn_mfma_f32_16x16x32_bf16(vf1, pf11, acc1[n2], 0, 0, 0);
    }
  }

  den0 += __shfl_xor(den0, 16, 64);
  den0 += __shfl_xor(den0, 32, 64);
  den1 += __shfl_xor(den1, 16, 64);
  den1 += __shfl_xor(den1, 32, 64);
  float inv0 = 1.f / (den0 + 1e-8f);
  float inv1 = 1.f / (den1 + 1e-8f);

  {
    int q0 = qt * QBLK + w * 16 + l16;
    float* dst0 = ctx + (size_t)(b * SEQ + q0) * D_MODEL + h * D_KH;
    float* dst1 = dst0 + (size_t)64 * D_MODEL;   // q0 + 64
    for (int n2 = 0; n2 < 4; ++n2) {
      f32x4 o0 = acc0[n2];
      f32x4 o1 = acc1[n2];
      *(float4*)(dst0 + n2 * 16 + quad * 4) =
          make_float4(o0[0] * inv0, o0[1] * inv0, o0[2] * inv0, o0[3] * inv0);
      *(float4*)(dst1 + n2 * 16 + quad * 4) =
          make_float4(o1[0] * inv1, o1[1] * inv1, o1[2] * inv1, o1[3] * inv1);
    }
  }
}

// ---------------------------------------------------------------- launch
extern "C" void kernel_launch(void* const* d_in, const int* in_sizes, int n_in,
                              void* d_out, int out_size, void* d_ws, size_t ws_size,
                              hipStream_t stream) {
  const float* Q      = (const float*)d_in[0];
  const int*   length = (const int*)d_in[1];
  const float* Wq     = (const float*)d_in[2];
  const float* bq     = (const float*)d_in[3];
  const float* Wk     = (const float*)d_in[4];
  const float* bk     = (const float*)d_in[5];
  const float* Wv     = (const float*)d_in[6];
  const float* bv     = (const float*)d_in[7];

  float* out_ctx = (float*)d_out;                         // [8192,1024]
  float* out_qa  = out_ctx + (size_t)M_TOTAL * D_MODEL;   // [8192,1024]

  char* ws = (char*)d_ws;
  unsigned short* Qbf = (unsigned short*)ws;                              // 16 MB
  unsigned short* WT  = (unsigned short*)(ws + (size_t)16 * 1024 * 1024); //  6 MB
  unsigned short* Kbf = (unsigned short*)(ws + (size_t)22 * 1024 * 1024); // 16 MB
  unsigned short* Vt  = (unsigned short*)(ws + (size_t)38 * 1024 * 1024); // 16 MB

  hipLaunchKernelGGL(cvt_all, dim3(8192 + 3072), dim3(256), 0, stream,
                     Q, Qbf, Wq, Wk, Wv, WT);
  hipLaunchKernelGGL(gemm_qkv, dim3(64 * 24), dim3(256), 0, stream,
                     Qbf, WT, bq, bk, bv, out_qa, Kbf, Vt);
  hipLaunchKernelGGL(attn, dim3(SEQ / QBLK, BATCH * N_HEADS), dim3(256), 0, stream,
                     out_qa, Kbf, Vt, length, out_ctx);
}